// Round 5
// baseline (362.228 us; speedup 1.0000x reference)
//
#include <hip/hip_runtime.h>

// HardMoE classifier: B=131072, D=768, E=6, L=2.
// Per row: 18 f32 dots of length 768 (6 gate + 12 dense expert), argmax-select.
// Memory-bound: 403 MB X read -> ~64us floor @ 6.3 TB/s.
// R5: weights entirely on the SCALAR pipe (s_load, uniform addrs, all f32),
//     LDS used only for x tiles (correct slot^=(row>>1) swizzle -> 2-way = free),
//     3 distinct LDS arrays + hand-rotated loop (no compiler vmcnt(0) insertion),
//     wait->stage(t+2)->compute = 2-tile prefetch distance, no barriers.

#define BB 131072
#define DD 768
#define ROWS 256            // threads per block = rows per block
#define TILE_D 16           // floats per staged d-tile
#define NT (DD / TILE_D)    // 48 tiles

#define GLOAD_LDS16(gsrc, ldst)                                                \
  __builtin_amdgcn_global_load_lds(                                            \
      (const __attribute__((address_space(1))) void*)(gsrc),                   \
      (__attribute__((address_space(3))) void*)(ldst), 16, 0, 0)

#define WAITV4 asm volatile("s_waitcnt vmcnt(4)" ::: "memory")
#define WAITV0 asm volatile("s_waitcnt vmcnt(0)" ::: "memory")

__global__ __launch_bounds__(ROWS, 2)
void HardMoE_kernel(const float* __restrict__ X,   // [B][768]
                    const float* __restrict__ gw,  // [6][768]
                    const float* __restrict__ gb,  // [6]
                    const float* __restrict__ ew,  // [6][768][2]
                    const float* __restrict__ eb,  // [6][2]
                    float* __restrict__ out)       // [B][2]
{
  // three distinct x-tile buffers (16 KB each) so LLVM alias analysis never
  // orders a ds_read against an outstanding global_load_lds to another buffer.
  __shared__ float xa[ROWS * TILE_D];
  __shared__ float xb[ROWS * TILE_D];
  __shared__ float xc[ROWS * TILE_D];

  const int tid  = threadIdx.x;
  const int lane = tid & 63;
  const int w    = tid >> 6;                  // wave 0..3
  const int row0 = blockIdx.x * ROWS;

  // LDS[r][p] holds chunk c=(p^(r>>1))&3 of row r (64 B/row/tile).
  // Writer lane l -> row base_r+(l>>2), slot p=l&3; base_r%16==0 so
  // (r>>1)&3 == (l>>3)&3  =>  fetch chunk c=(l&3)^((l>>3)&3).
  auto stage = [&](float* dst, int tile) {
#pragma unroll
    for (int i = 0; i < 4; ++i) {
      const int base_r = w * 64 + i * 16;                 // wave-uniform
      const int r      = base_r + (lane >> 2);
      const int c      = (lane & 3) ^ ((lane >> 3) & 3);  // pre-swizzled source
      GLOAD_LDS16(X + (size_t)(row0 + r) * DD + tile * TILE_D + c * 4,
                  dst + base_r * TILE_D);
    }
  };

  float acc[18];     // 0..5 gate, 6..17 expert (e*2+l), all f32
#pragma unroll
  for (int j = 0; j < 18; ++j) acc[j] = 0.f;

  const int tsw = (tid >> 1) & 3;             // per-thread read-swizzle key

  auto step = [&](const float* cur, float* stg, int t) {
    if (t + 1 < NT) { WAITV4; } else { WAITV0; }          // s(t) landed
    if (t + 2 < NT) stage(stg, t + 2);                    // 2-tile prefetch
    const int d0 = t * TILE_D;
#pragma unroll
    for (int g = 0; g < 4; ++g) {
      // un-swizzle: chunk g lives at slot g^tsw (2-way banks = free)
      const float4 xv = *(const float4*)(cur + (tid << 4) + (((g ^ tsw) & 3) << 2));
      const int d = d0 + (g << 2);
#pragma unroll
      for (int j = 0; j < 6; ++j) {           // gate: uniform -> s_load_dwordx4
        const float4 wv = *(const float4*)(gw + j * DD + d);
        acc[j] += xv.x * wv.x + xv.y * wv.y + xv.z * wv.z + xv.w * wv.w;
      }
#pragma unroll
      for (int e = 0; e < 6; ++e) {           // experts: uniform -> s_load_dwordx8
        const float* wb = ew + ((e * DD + d) << 1);       // [d][l] interleaved
        const float4 a  = *(const float4*)(wb);
        const float4 b  = *(const float4*)(wb + 4);
        acc[6 + 2 * e] += xv.x * a.x + xv.y * a.z + xv.z * b.x + xv.w * b.z;
        acc[7 + 2 * e] += xv.x * a.y + xv.y * a.w + xv.z * b.y + xv.w * b.w;
      }
    }
  };

  stage(xa, 0);
  stage(xb, 1);

  for (int tt = 0; tt < NT; tt += 3) {        // buffers rotate with period 3
    step(xa, xc, tt);                         // reads t%3==0, stages (t+2)%3==2
    step(xb, xa, tt + 1);
    step(xc, xb, tt + 2);
  }

  // ---- epilogue: argmax (first-max rule = jnp.argmax) + select + store ----
  float gbv[6], ebv[12];
#pragma unroll
  for (int j = 0; j < 6; ++j) gbv[j] = gb[j];
#pragma unroll
  for (int i = 0; i < 12; ++i) ebv[i] = eb[i];

  int   best = 0;
  float bv   = acc[0] + gbv[0];
#pragma unroll
  for (int j = 1; j < 6; ++j) {
    const float v = acc[j] + gbv[j];
    if (v > bv) { bv = v; best = j; }
  }
  float o0 = acc[6] + ebv[0], o1 = acc[7] + ebv[1];
#pragma unroll
  for (int e = 1; e < 6; ++e) {
    const bool s = (best == e);
    o0 = s ? acc[6 + 2 * e] + ebv[2 * e]     : o0;
    o1 = s ? acc[7 + 2 * e] + ebv[2 * e + 1] : o1;
  }

  ((float2*)out)[row0 + tid] = make_float2(o0, o1);
}

extern "C" void kernel_launch(void* const* d_in, const int* in_sizes, int n_in,
                              void* d_out, int out_size, void* d_ws, size_t ws_size,
                              hipStream_t stream) {
  (void)in_sizes; (void)n_in; (void)d_ws; (void)ws_size; (void)out_size;
  const float* X  = (const float*)d_in[0];
  const float* gw = (const float*)d_in[1];
  const float* gb = (const float*)d_in[2];
  const float* ew = (const float*)d_in[3];
  const float* eb = (const float*)d_in[4];
  float* out = (float*)d_out;
  HardMoE_kernel<<<BB / ROWS, ROWS, 0, stream>>>(X, gw, gb, ew, eb, out);
}

// Round 7
// 109.508 us; speedup vs baseline: 3.3078x; 3.3078x over previous
//
#include <hip/hip_runtime.h>

// HardMoE classifier: B=131072, D=768, E=6, L=2  ==  skinny GEMM 131072x30x768.
// R7: MFMA v_mfma_f32_32x32x16_bf16. One wave = 32-row tile, all 30 output
//     cols in one accumulator. 3-way bf16 split (hi/mid/lo) of X and gate-W
//     makes the gate f32-accurate (no argmax flips); experts exact-X * bf16-W.
//     X loaded DIRECT from global in fragment layout (no x LDS, no staging);
//     W fragments from LDS (k-octet-major => conflict-free ds_read_b128).
//     No in-loop s_loads, no barriers after prologue.

#define BB 131072
#define DD 768
#define NSTEP 48            // K-steps of 16
#define ROWS_PER_BLOCK 256  // 4 waves x 2 tiles x 32 rows

typedef __bf16 bf16x8 __attribute__((ext_vector_type(8)));
typedef float floatx16 __attribute__((ext_vector_type(16)));
typedef unsigned short ushortx8 __attribute__((ext_vector_type(8)));

__device__ __forceinline__ unsigned bf16_rne(float x) {
  const unsigned u = __builtin_bit_cast(unsigned, x);
  return (u + 0x7fffu + ((u >> 16) & 1u)) >> 16;
}

// x -> hi + mid + lo (each bf16-trunc), residual ~2^-24 |x|
__device__ __forceinline__ void cvt3(const float4& a, const float4& b,
                                     bf16x8& H, bf16x8& M, bf16x8& L) {
  const float v[8] = {a.x, a.y, a.z, a.w, b.x, b.y, b.z, b.w};
  ushortx8 h, m, l;
#pragma unroll
  for (int j = 0; j < 8; ++j) {
    const float x = v[j];
    const unsigned ub = __builtin_bit_cast(unsigned, x);
    const float rm = x - __builtin_bit_cast(float, ub & 0xffff0000u);
    const unsigned mb = __builtin_bit_cast(unsigned, rm);
    const float rl = rm - __builtin_bit_cast(float, mb & 0xffff0000u);
    h[j] = (unsigned short)(ub >> 16);
    m[j] = (unsigned short)(mb >> 16);
    l[j] = (unsigned short)(__builtin_bit_cast(unsigned, rl) >> 16);
  }
  H = __builtin_bit_cast(bf16x8, h);
  M = __builtin_bit_cast(bf16x8, m);
  L = __builtin_bit_cast(bf16x8, l);
}

__global__ __launch_bounds__(256, 2)
void HardMoE_kernel(const float* __restrict__ X,   // [B][768]
                    const float* __restrict__ gw,  // [6][768]
                    const float* __restrict__ gb,  // [6]
                    const float* __restrict__ ew,  // [6][768][2]
                    const float* __restrict__ eb,  // [6][2]
                    float* __restrict__ out)       // [B][2]
{
  // W tile, k-octet-major: [oct 0..95][col 0..31][8 bf16] -> frag read is
  // lanes 0..31 = cols * 16B = perfectly linear (conflict-free). 48 KB.
  __shared__ unsigned wt[96 * 32 * 4];
  // per-wave C scratch [32 rows][32 cols] f32, 16B-slot XOR swizzle. 16 KB.
  __shared__ float ct[4][32 * 32];

  const int tid  = threadIdx.x;
  const int lane = tid & 63;
  const int w    = tid >> 6;
  const int mrow = lane & 31;   // row within 32-row tile; also B-frag col
  const int koct = lane >> 5;   // which k-octet of the 16-k step

  // ---- prologue: build split-W in LDS ----
  // cols 0-5 gate_hi, 6-11 gate_mid, 12-17 gate_lo, 18-29 expert(e*2+l), 30-31 zero
  for (int u = tid; u < 96 * 32 * 4; u += 256) {
    const int pair = u & 3;            // 2-k pair within octet
    const int col  = (u >> 2) & 31;
    const int oct  = u >> 7;
    const int k0   = oct * 8 + pair * 2;
    unsigned val = 0;
    if (col < 18) {
      const int part = col / 6, j = col % 6;
      const float w0 = gw[j * DD + k0], w1 = gw[j * DD + k0 + 1];
      const unsigned u0 = __builtin_bit_cast(unsigned, w0);
      const unsigned u1 = __builtin_bit_cast(unsigned, w1);
      const float rm0 = w0 - __builtin_bit_cast(float, u0 & 0xffff0000u);
      const float rm1 = w1 - __builtin_bit_cast(float, u1 & 0xffff0000u);
      const unsigned m0 = __builtin_bit_cast(unsigned, rm0);
      const unsigned m1 = __builtin_bit_cast(unsigned, rm1);
      const float rl0 = rm0 - __builtin_bit_cast(float, m0 & 0xffff0000u);
      const float rl1 = rm1 - __builtin_bit_cast(float, m1 & 0xffff0000u);
      const unsigned l0 = __builtin_bit_cast(unsigned, rl0);
      const unsigned l1 = __builtin_bit_cast(unsigned, rl1);
      if (part == 0)      val = (u0 >> 16) | (u1 & 0xffff0000u);
      else if (part == 1) val = (m0 >> 16) | (m1 & 0xffff0000u);
      else                val = (l0 >> 16) | (l1 & 0xffff0000u);
    } else if (col < 30) {
      const int e = (col - 18) >> 1, l = (col - 18) & 1;
      const float w0 = ew[(e * DD + k0) * 2 + l];
      const float w1 = ew[(e * DD + k0 + 1) * 2 + l];
      val = bf16_rne(w0) | (bf16_rne(w1) << 16);
    }
    wt[u] = val;   // byte addr = u*4 = oct*512 + col*16 + pair*4  (linear)
  }
  __syncthreads();   // only barrier in the kernel

  const uint4* wtv = (const uint4*)wt;

#pragma unroll 1
  for (int mt = 0; mt < 2; ++mt) {
    const int rbase = blockIdx.x * ROWS_PER_BLOCK + w * 64 + mt * 32;
    const float* xr = X + (size_t)(rbase + mrow) * DD + koct * 8;

    floatx16 acc;
#pragma unroll
    for (int j = 0; j < 16; ++j) acc[j] = 0.f;

    // software pipeline: 2 steps resident, prefetch 2 ahead
    float4 a0 = *(const float4*)(xr);
    float4 b0 = *(const float4*)(xr + 4);
    float4 a1 = *(const float4*)(xr + 16);
    float4 b1 = *(const float4*)(xr + 20);

    for (int t = 0; t < NSTEP; t += 2) {
      float4 na0, nb0, na1, nb1;
      if (t + 2 < NSTEP) {
        na0 = *(const float4*)(xr + (t + 2) * 16);
        nb0 = *(const float4*)(xr + (t + 2) * 16 + 4);
        na1 = *(const float4*)(xr + (t + 3) * 16);
        nb1 = *(const float4*)(xr + (t + 3) * 16 + 4);
      }
      {
        const bf16x8 bv = __builtin_bit_cast(bf16x8, wtv[(2 * t + koct) * 32 + mrow]);
        bf16x8 xh, xm, xl;
        cvt3(a0, b0, xh, xm, xl);
        acc = __builtin_amdgcn_mfma_f32_32x32x16_bf16(xh, bv, acc, 0, 0, 0);
        acc = __builtin_amdgcn_mfma_f32_32x32x16_bf16(xm, bv, acc, 0, 0, 0);
        acc = __builtin_amdgcn_mfma_f32_32x32x16_bf16(xl, bv, acc, 0, 0, 0);
      }
      {
        const bf16x8 bv = __builtin_bit_cast(bf16x8, wtv[(2 * (t + 1) + koct) * 32 + mrow]);
        bf16x8 xh, xm, xl;
        cvt3(a1, b1, xh, xm, xl);
        acc = __builtin_amdgcn_mfma_f32_32x32x16_bf16(xh, bv, acc, 0, 0, 0);
        acc = __builtin_amdgcn_mfma_f32_32x32x16_bf16(xm, bv, acc, 0, 0, 0);
        acc = __builtin_amdgcn_mfma_f32_32x32x16_bf16(xl, bv, acc, 0, 0, 0);
      }
      a0 = na0; b0 = nb0; a1 = na1; b1 = nb1;
    }

    // ---- epilogue: C layout col=lane&31, row=(reg&3)+8*(reg>>2)+4*koct ----
    float* cw = &ct[w][0];
#pragma unroll
    for (int reg = 0; reg < 16; ++reg) {
      const int r = (reg & 3) + 8 * (reg >> 2) + 4 * koct;
      const int byteoff = r * 128 + ((mrow * 4) ^ ((r & 7) << 4));  // slot swizzle
      *(float*)((char*)cw + byteoff) = acc[reg];
    }
    // same-wave LDS ordering: reads below depend on writes above (compiler waits)
    if (lane < 32) {
      const int r = lane;
      float cv[32];
#pragma unroll
      for (int j = 0; j < 8; ++j) {
        const float4 q = *(const float4*)((const char*)cw + r * 128 +
                                          ((j * 16) ^ ((r & 7) << 4)));
        cv[4 * j] = q.x; cv[4 * j + 1] = q.y; cv[4 * j + 2] = q.z; cv[4 * j + 3] = q.w;
      }
      float g[6];
#pragma unroll
      for (int c = 0; c < 6; ++c) g[c] = cv[c] + cv[6 + c] + cv[12 + c] + gb[c];
      int best = 0; float bv = g[0];
#pragma unroll
      for (int c = 1; c < 6; ++c) { if (g[c] > bv) { bv = g[c]; best = c; } }
      float ebv[12];
#pragma unroll
      for (int i = 0; i < 12; ++i) ebv[i] = eb[i];
      float o0 = cv[18] + ebv[0], o1 = cv[19] + ebv[1];
#pragma unroll
      for (int e = 1; e < 6; ++e) {
        const bool s = (best == e);
        o0 = s ? cv[18 + 2 * e] + ebv[2 * e]     : o0;
        o1 = s ? cv[19 + 2 * e] + ebv[2 * e + 1] : o1;
      }
      ((float2*)out)[rbase + r] = make_float2(o0, o1);
    }
  }
}

extern "C" void kernel_launch(void* const* d_in, const int* in_sizes, int n_in,
                              void* d_out, int out_size, void* d_ws, size_t ws_size,
                              hipStream_t stream) {
  (void)in_sizes; (void)n_in; (void)d_ws; (void)ws_size; (void)out_size;
  const float* X  = (const float*)d_in[0];
  const float* gw = (const float*)d_in[1];
  const float* gb = (const float*)d_in[2];
  const float* ew = (const float*)d_in[3];
  const float* eb = (const float*)d_in[4];
  float* out = (float*)d_out;
  HardMoE_kernel<<<BB / ROWS_PER_BLOCK, 256, 0, stream>>>(X, gw, gb, ew, eb, out);
}

// Round 8
// 106.389 us; speedup vs baseline: 3.4048x; 1.0293x over previous
//
#include <hip/hip_runtime.h>

// HardMoE classifier: B=131072, D=768, E=6, L=2 == skinny GEMM 131072x30x768.
// R8: R7's MFMA core, restructured for occupancy + prefetch depth:
//  - W image (96 octets x 32 cols x 16B, 3-way-split gate + bf16 experts)
//    pre-packed ONCE into d_ws by a 48-block kernel; main kernel streams W
//    fragments directly from L2 (48 KB resident) -> zero weight-LDS, zero
//    pack prologue, no barriers before the epilogue.
//  - LDS = per-wave C scratch only (16 KB/block) -> 4 blocks/CU (16 waves).
//  - One 32-row tile per wave (grid 1024), single K-loop, X+W prefetch
//    4 steps deep (~920 cyc >= 900 cyc HBM latency), static reg indexing.
// Numerics identical to R7 (passed, absmax 0.0156 = expert bf16-W rounding).

#define BB 131072
#define DD 768
#define NSTEP 48            // K-steps of 16
#define RPB 128             // rows per block: 4 waves x 32
#define WTU (96 * 32 * 4)   // uints in packed W image (48 KB)

typedef __bf16 bf16x8 __attribute__((ext_vector_type(8)));
typedef float floatx16 __attribute__((ext_vector_type(16)));
typedef unsigned short ushortx8 __attribute__((ext_vector_type(8)));

__device__ __forceinline__ unsigned bf16_rne(float x) {
  const unsigned u = __builtin_bit_cast(unsigned, x);
  return (u + 0x7fffu + ((u >> 16) & 1u)) >> 16;
}

// x -> hi + mid + lo (bf16-trunc each), residual ~2^-25 |x|
__device__ __forceinline__ void cvt3(const float4& a, const float4& b,
                                     bf16x8& H, bf16x8& M, bf16x8& L) {
  const float v[8] = {a.x, a.y, a.z, a.w, b.x, b.y, b.z, b.w};
  ushortx8 h, m, l;
#pragma unroll
  for (int j = 0; j < 8; ++j) {
    const float x = v[j];
    const unsigned ub = __builtin_bit_cast(unsigned, x);
    const float rm = x - __builtin_bit_cast(float, ub & 0xffff0000u);
    const unsigned mb = __builtin_bit_cast(unsigned, rm);
    const float rl = rm - __builtin_bit_cast(float, mb & 0xffff0000u);
    h[j] = (unsigned short)(ub >> 16);
    m[j] = (unsigned short)(mb >> 16);
    l[j] = (unsigned short)(__builtin_bit_cast(unsigned, rl) >> 16);
  }
  H = __builtin_bit_cast(bf16x8, h);
  M = __builtin_bit_cast(bf16x8, m);
  L = __builtin_bit_cast(bf16x8, l);
}

// ---- kernel 1: pack W image into d_ws ----
// cols 0-5 gate_hi, 6-11 gate_mid, 12-17 gate_lo, 18-29 expert(e*2+l), 30-31 0.
// word u: pair=u&3, col=(u>>2)&31, oct=u>>7; byte addr u*4 = oct*512+col*16+pair*4.
__global__ void pack_w_kernel(const float* __restrict__ gw,
                              const float* __restrict__ ew,
                              unsigned* __restrict__ wt) {
  const int u = blockIdx.x * 256 + threadIdx.x;
  if (u >= WTU) return;
  const int pair = u & 3;
  const int col  = (u >> 2) & 31;
  const int oct  = u >> 7;
  const int k0   = oct * 8 + pair * 2;
  unsigned val = 0;
  if (col < 18) {
    const int part = col / 6, j = col % 6;
    const float w0 = gw[j * DD + k0], w1 = gw[j * DD + k0 + 1];
    const unsigned u0 = __builtin_bit_cast(unsigned, w0);
    const unsigned u1 = __builtin_bit_cast(unsigned, w1);
    const float rm0 = w0 - __builtin_bit_cast(float, u0 & 0xffff0000u);
    const float rm1 = w1 - __builtin_bit_cast(float, u1 & 0xffff0000u);
    const unsigned m0 = __builtin_bit_cast(unsigned, rm0);
    const unsigned m1 = __builtin_bit_cast(unsigned, rm1);
    const float rl0 = rm0 - __builtin_bit_cast(float, m0 & 0xffff0000u);
    const float rl1 = rm1 - __builtin_bit_cast(float, m1 & 0xffff0000u);
    const unsigned l0 = __builtin_bit_cast(unsigned, rl0);
    const unsigned l1 = __builtin_bit_cast(unsigned, rl1);
    if (part == 0)      val = (u0 >> 16) | (u1 & 0xffff0000u);
    else if (part == 1) val = (m0 >> 16) | (m1 & 0xffff0000u);
    else                val = (l0 >> 16) | (l1 & 0xffff0000u);
  } else if (col < 30) {
    const int e = (col - 18) >> 1, l = (col - 18) & 1;
    val = bf16_rne(ew[(e * DD + k0) * 2 + l]) |
          (bf16_rne(ew[(e * DD + k0 + 1) * 2 + l]) << 16);
  }
  wt[u] = val;
}

// ---- kernel 2: main GEMM + argmax-select ----
__global__ __launch_bounds__(256, 4)
void HardMoE_kernel(const float* __restrict__ X,     // [B][768]
                    const unsigned* __restrict__ wtg,// packed W image (d_ws)
                    const float* __restrict__ gb,    // [6]
                    const float* __restrict__ eb,    // [6][2]
                    float* __restrict__ out)         // [B][2]
{
  __shared__ float ct[4][32 * 32];   // per-wave C scratch, 16B-granule XOR swz

  const int tid  = threadIdx.x;
  const int lane = tid & 63;
  const int w    = tid >> 6;
  const int mrow = lane & 31;        // A row within tile; B col
  const int koct = lane >> 5;        // k-octet of the 16-k step

  const int rbase = blockIdx.x * RPB + w * 32;
  const float* xr = X + (size_t)(rbase + mrow) * DD + koct * 8;
  const uint4* wtv = (const uint4*)wtg;

  floatx16 acc;
#pragma unroll
  for (int j = 0; j < 16; ++j) acc[j] = 0.f;

  // 4-step-deep rotating prefetch (static indices only)
  float4 xa[4], xb[4];
  uint4  wv[4];
#pragma unroll
  for (int i = 0; i < 4; ++i) {
    xa[i] = *(const float4*)(xr + i * 16);
    xb[i] = *(const float4*)(xr + i * 16 + 4);
    wv[i] = wtv[(2 * i + koct) * 32 + mrow];
  }

  for (int t = 0; t < NSTEP; t += 4) {
#pragma unroll
    for (int u = 0; u < 4; ++u) {
      bf16x8 xh, xm, xl;
      cvt3(xa[u], xb[u], xh, xm, xl);
      const bf16x8 bv = __builtin_bit_cast(bf16x8, wv[u]);
      acc = __builtin_amdgcn_mfma_f32_32x32x16_bf16(xh, bv, acc, 0, 0, 0);
      acc = __builtin_amdgcn_mfma_f32_32x32x16_bf16(xm, bv, acc, 0, 0, 0);
      acc = __builtin_amdgcn_mfma_f32_32x32x16_bf16(xl, bv, acc, 0, 0, 0);
      const int tn = t + u + 4;
      if (tn < NSTEP) {                      // wave-uniform branch
        xa[u] = *(const float4*)(xr + tn * 16);
        xb[u] = *(const float4*)(xr + tn * 16 + 4);
        wv[u] = wtv[(2 * tn + koct) * 32 + mrow];
      }
    }
  }

  // ---- epilogue (R7-verified): C col=lane&31, row=(reg&3)+8*(reg>>2)+4*koct
  float* cw = &ct[w][0];
#pragma unroll
  for (int reg = 0; reg < 16; ++reg) {
    const int r = (reg & 3) + 8 * (reg >> 2) + 4 * koct;
    const int byteoff = r * 128 + ((mrow * 4) ^ ((r & 7) << 4));
    *(float*)((char*)cw + byteoff) = acc[reg];
  }
  // same-wave LDS write->read dependency; compiler inserts lgkmcnt wait
  if (lane < 32) {
    const int r = lane;
    float cv[32];
#pragma unroll
    for (int j = 0; j < 8; ++j) {
      const float4 q = *(const float4*)((const char*)cw + r * 128 +
                                        ((j * 16) ^ ((r & 7) << 4)));
      cv[4 * j] = q.x; cv[4 * j + 1] = q.y; cv[4 * j + 2] = q.z; cv[4 * j + 3] = q.w;
    }
    float g[6];
#pragma unroll
    for (int c = 0; c < 6; ++c) g[c] = cv[c] + cv[6 + c] + cv[12 + c] + gb[c];
    int best = 0; float bv = g[0];
#pragma unroll
    for (int c = 1; c < 6; ++c) { if (g[c] > bv) { bv = g[c]; best = c; } }
    float ebv[12];
#pragma unroll
    for (int i = 0; i < 12; ++i) ebv[i] = eb[i];
    float o0 = cv[18] + ebv[0], o1 = cv[19] + ebv[1];
#pragma unroll
    for (int e = 1; e < 6; ++e) {
      const bool s = (best == e);
      o0 = s ? cv[18 + 2 * e] + ebv[2 * e]     : o0;
      o1 = s ? cv[19 + 2 * e] + ebv[2 * e + 1] : o1;
    }
    ((float2*)out)[rbase + r] = make_float2(o0, o1);
  }
}

extern "C" void kernel_launch(void* const* d_in, const int* in_sizes, int n_in,
                              void* d_out, int out_size, void* d_ws, size_t ws_size,
                              hipStream_t stream) {
  (void)in_sizes; (void)n_in; (void)ws_size; (void)out_size;
  const float* X  = (const float*)d_in[0];
  const float* gw = (const float*)d_in[1];
  const float* gb = (const float*)d_in[2];
  const float* ew = (const float*)d_in[3];
  const float* eb = (const float*)d_in[4];
  float* out = (float*)d_out;
  unsigned* wt = (unsigned*)d_ws;   // needs 48 KB

  pack_w_kernel<<<WTU / 256, 256, 0, stream>>>(gw, ew, wt);
  HardMoE_kernel<<<BB / RPB, 256, 0, stream>>>(X, wt, gb, eb, out);
}

// Round 9
// 81.033 us; speedup vs baseline: 4.4701x; 1.3129x over previous
//
#include <hip/hip_runtime.h>

// HardMoE classifier: B=131072, D=768, E=6, L=2 == skinny GEMM 131072x30x768.
// R9: R8's MFMA core (3-way-split gate, bf16 experts, pre-packed W in d_ws),
//     but X now staged via global_load_lds in CONTIGUOUS 256B/row segments
//     (channel-uniform HBM traffic; R7/R8's stride-3072 64B-segment pattern
//     clumped onto ~1/4 of the HBM pseudo-channels -> 3.8 TB/s cap).
//  - per-wave 32-row tile; K processed in 12 supers of 4 K16-steps;
//    wave-staggered super order ((s+3w) mod 12) decorrelates channel phase.
//  - LDS spans 1040B (pad 16) -> balanced conflict-free ds_read_b128;
//    dest linear per rule 21. Wave-private double buffer, no barriers,
//    counted vmcnt(12) = 8 stage + 4 W loads in flight.

#define BB 131072
#define DD 768
#define RPB 128             // rows per block = 4 waves x 32
#define NSUP 12             // K supers (4 x 16-k steps each)
#define SPAN 1040           // 1024B staged + 16B pad (bank-phase shift)
#define BUFO 8320           // 8 spans per buffer
#define WREG 16640          // per-wave LDS: 2 buffers
#define WTU (96 * 32 * 4)   // uints in packed W image (48 KB)

typedef __bf16 bf16x8 __attribute__((ext_vector_type(8)));
typedef float floatx16 __attribute__((ext_vector_type(16)));
typedef unsigned short ushortx8 __attribute__((ext_vector_type(8)));

#define GLOAD_LDS16(gsrc, ldst)                                                \
  __builtin_amdgcn_global_load_lds(                                            \
      (const __attribute__((address_space(1))) void*)(gsrc),                   \
      (__attribute__((address_space(3))) void*)(ldst), 16, 0, 0)

#define WAITV12 asm volatile("s_waitcnt vmcnt(12)" ::: "memory")
#define WAITV0  asm volatile("s_waitcnt vmcnt(0)" ::: "memory")

__device__ __forceinline__ unsigned bf16_rne(float x) {
  const unsigned u = __builtin_bit_cast(unsigned, x);
  return (u + 0x7fffu + ((u >> 16) & 1u)) >> 16;
}

// x -> hi + mid + lo (bf16-trunc each); gate recovers full f32 product.
__device__ __forceinline__ void cvt3(const float4& a, const float4& b,
                                     bf16x8& H, bf16x8& M, bf16x8& L) {
  const float v[8] = {a.x, a.y, a.z, a.w, b.x, b.y, b.z, b.w};
  ushortx8 h, m, l;
#pragma unroll
  for (int j = 0; j < 8; ++j) {
    const float x = v[j];
    const unsigned ub = __builtin_bit_cast(unsigned, x);
    const float rm = x - __builtin_bit_cast(float, ub & 0xffff0000u);
    const unsigned mb = __builtin_bit_cast(unsigned, rm);
    const float rl = rm - __builtin_bit_cast(float, mb & 0xffff0000u);
    h[j] = (unsigned short)(ub >> 16);
    m[j] = (unsigned short)(mb >> 16);
    l[j] = (unsigned short)(__builtin_bit_cast(unsigned, rl) >> 16);
  }
  H = __builtin_bit_cast(bf16x8, h);
  M = __builtin_bit_cast(bf16x8, m);
  L = __builtin_bit_cast(bf16x8, l);
}

// ---- kernel 1: pack W image into d_ws (R8-verified) ----
// cols 0-5 gate_hi, 6-11 gate_mid, 12-17 gate_lo, 18-29 expert(e*2+l), 30-31 0.
__global__ void pack_w_kernel(const float* __restrict__ gw,
                              const float* __restrict__ ew,
                              unsigned* __restrict__ wt) {
  const int u = blockIdx.x * 256 + threadIdx.x;
  if (u >= WTU) return;
  const int pair = u & 3;
  const int col  = (u >> 2) & 31;
  const int oct  = u >> 7;
  const int k0   = oct * 8 + pair * 2;
  unsigned val = 0;
  if (col < 18) {
    const int part = col / 6, j = col % 6;
    const float w0 = gw[j * DD + k0], w1 = gw[j * DD + k0 + 1];
    const unsigned u0 = __builtin_bit_cast(unsigned, w0);
    const unsigned u1 = __builtin_bit_cast(unsigned, w1);
    const float rm0 = w0 - __builtin_bit_cast(float, u0 & 0xffff0000u);
    const float rm1 = w1 - __builtin_bit_cast(float, u1 & 0xffff0000u);
    const unsigned m0 = __builtin_bit_cast(unsigned, rm0);
    const unsigned m1 = __builtin_bit_cast(unsigned, rm1);
    const float rl0 = rm0 - __builtin_bit_cast(float, m0 & 0xffff0000u);
    const float rl1 = rm1 - __builtin_bit_cast(float, m1 & 0xffff0000u);
    const unsigned l0 = __builtin_bit_cast(unsigned, rl0);
    const unsigned l1 = __builtin_bit_cast(unsigned, rl1);
    if (part == 0)      val = (u0 >> 16) | (u1 & 0xffff0000u);
    else if (part == 1) val = (m0 >> 16) | (m1 & 0xffff0000u);
    else                val = (l0 >> 16) | (l1 & 0xffff0000u);
  } else if (col < 30) {
    const int e = (col - 18) >> 1, l = (col - 18) & 1;
    val = bf16_rne(ew[(e * DD + k0) * 2 + l]) |
          (bf16_rne(ew[(e * DD + k0 + 1) * 2 + l]) << 16);
  }
  wt[u] = val;
}

// ---- kernel 2: main GEMM + argmax-select ----
__global__ __launch_bounds__(256, 2)
void HardMoE_kernel(const float* __restrict__ X,      // [B][768]
                    const unsigned* __restrict__ wtg, // packed W (d_ws)
                    const float* __restrict__ gb,     // [6]
                    const float* __restrict__ eb,     // [6][2]
                    float* __restrict__ out)          // [B][2]
{
  __shared__ char xlds[4 * WREG];   // 66560 B; wave-private regions

  const int tid  = threadIdx.x;
  const int lane = tid & 63;
  const int w    = tid >> 6;
  const int mrow = lane & 31;       // A row in tile; B col
  const int koct = lane >> 5;       // k-octet of the 16-k step

  const int rbase = blockIdx.x * RPB + w * 32;
  char* wb = xlds + w * WREG;
  const float* Xw = X + (size_t)rbase * DD;
  // staging: inst i covers rows 4i..4i+3, 256B contiguous per row
  const int rowoff = (lane >> 4) * DD + (lane & 15) * 4;
  // read: lane's 32B of step t lives at rdoff + t*64 (+16)
  const int rdoff  = (mrow >> 2) * SPAN + (mrow & 3) * 256 + koct * 32;
  const uint4* wtv = (const uint4*)wtg;
  const int wfo = koct * 32 + mrow; // W frag idx = (q*4+t)*64 + wfo

  auto stage = [&](int bufo, int q) {
#pragma unroll
    for (int i = 0; i < 8; ++i)
      GLOAD_LDS16(Xw + i * 4 * DD + q * 64 + rowoff,
                  wb + bufo + i * SPAN + lane * 16);
  };

  floatx16 acc;
#pragma unroll
  for (int j = 0; j < 16; ++j) acc[j] = 0.f;

  uint4 wvA[4], wvB[4];

  int q0 = 3 * w;                    // stagger: waves at different mod-4 phase
  if (q0 >= NSUP) q0 -= NSUP;
  stage(0, q0);
#pragma unroll
  for (int t = 0; t < 4; ++t) wvA[t] = wtv[(q0 * 4 + t) * 64 + wfo];
  int q1 = (q0 + 1 == NSUP) ? 0 : q0 + 1;
  stage(BUFO, q1);
#pragma unroll
  for (int t = 0; t < 4; ++t) wvB[t] = wtv[(q1 * 4 + t) * 64 + wfo];
  int qn = (q1 + 1 == NSUP) ? 0 : q1 + 1;

#define STEP3(bufo, t, WVt)                                                    \
  {                                                                            \
    const char* p = wb + (bufo) + rdoff + (t) * 64;                            \
    const float4 x0 = *(const float4*)p;                                       \
    const float4 x1 = *(const float4*)(p + 16);                                \
    bf16x8 xh, xm, xl;                                                         \
    cvt3(x0, x1, xh, xm, xl);                                                  \
    const bf16x8 bv = __builtin_bit_cast(bf16x8, WVt);                         \
    acc = __builtin_amdgcn_mfma_f32_32x32x16_bf16(xh, bv, acc, 0, 0, 0);       \
    acc = __builtin_amdgcn_mfma_f32_32x32x16_bf16(xm, bv, acc, 0, 0, 0);       \
    acc = __builtin_amdgcn_mfma_f32_32x32x16_bf16(xl, bv, acc, 0, 0, 0);       \
  }

#pragma unroll 1
  for (int ss = 0; ss < 6; ++ss) {
    WAITV12;                              // super 2ss landed (stage+W)
    STEP3(0, 0, wvA[0]) STEP3(0, 1, wvA[1])
    STEP3(0, 2, wvA[2]) STEP3(0, 3, wvA[3])
    if (ss < 5) {
      stage(0, qn);                       // refill buffer A (just freed)
#pragma unroll
      for (int t = 0; t < 4; ++t) wvA[t] = wtv[(qn * 4 + t) * 64 + wfo];
      qn = (qn + 1 == NSUP) ? 0 : qn + 1;
    }
    if (ss < 5) { WAITV12; } else { WAITV0; }   // super 2ss+1 landed
    STEP3(BUFO, 0, wvB[0]) STEP3(BUFO, 1, wvB[1])
    STEP3(BUFO, 2, wvB[2]) STEP3(BUFO, 3, wvB[3])
    if (ss < 5) {
      stage(BUFO, qn);
#pragma unroll
      for (int t = 0; t < 4; ++t) wvB[t] = wtv[(qn * 4 + t) * 64 + wfo];
      qn = (qn + 1 == NSUP) ? 0 : qn + 1;
    }
  }
#undef STEP3

  // ---- epilogue (R7/R8-verified): C col=lane&31, row=(reg&3)+8*(reg>>2)+4*koct
  float* cw = (float*)(xlds + w * WREG);  // reuse wave's own region
#pragma unroll
  for (int reg = 0; reg < 16; ++reg) {
    const int r = (reg & 3) + 8 * (reg >> 2) + 4 * koct;
    const int byteoff = r * 128 + ((mrow * 4) ^ ((r & 7) << 4));
    *(float*)((char*)cw + byteoff) = acc[reg];
  }
  if (lane < 32) {
    const int r = lane;
    float cv[32];
#pragma unroll
    for (int j = 0; j < 8; ++j) {
      const float4 qv = *(const float4*)((const char*)cw + r * 128 +
                                         ((j * 16) ^ ((r & 7) << 4)));
      cv[4 * j] = qv.x; cv[4 * j + 1] = qv.y;
      cv[4 * j + 2] = qv.z; cv[4 * j + 3] = qv.w;
    }
    float g[6];
#pragma unroll
    for (int c = 0; c < 6; ++c) g[c] = cv[c] + cv[6 + c] + cv[12 + c] + gb[c];
    int best = 0; float bv = g[0];
#pragma unroll
    for (int c = 1; c < 6; ++c) { if (g[c] > bv) { bv = g[c]; best = c; } }
    float ebv[12];
#pragma unroll
    for (int i = 0; i < 12; ++i) ebv[i] = eb[i];
    float o0 = cv[18] + ebv[0], o1 = cv[19] + ebv[1];
#pragma unroll
    for (int e = 1; e < 6; ++e) {
      const bool s = (best == e);
      o0 = s ? cv[18 + 2 * e] + ebv[2 * e]     : o0;
      o1 = s ? cv[19 + 2 * e] + ebv[2 * e + 1] : o1;
    }
    ((float2*)out)[rbase + r] = make_float2(o0, o1);
  }
}

extern "C" void kernel_launch(void* const* d_in, const int* in_sizes, int n_in,
                              void* d_out, int out_size, void* d_ws, size_t ws_size,
                              hipStream_t stream) {
  (void)in_sizes; (void)n_in; (void)ws_size; (void)out_size;
  const float* X  = (const float*)d_in[0];
  const float* gw = (const float*)d_in[1];
  const float* gb = (const float*)d_in[2];
  const float* ew = (const float*)d_in[3];
  const float* eb = (const float*)d_in[4];
  float* out = (float*)d_out;
  unsigned* wt = (unsigned*)d_ws;   // 48 KB

  pack_w_kernel<<<WTU / 256, 256, 0, stream>>>(gw, ew, wt);
  HardMoE_kernel<<<BB / RPB, 256, 0, stream>>>(X, wt, gb, eb, out);
}

// Round 10
// 80.702 us; speedup vs baseline: 4.4885x; 1.0041x over previous
//
#include <hip/hip_runtime.h>

// HardMoE classifier: B=131072, D=768, E=6, L=2 == skinny GEMM 131072x30x768.
// R10: R9 (channel-uniform 256B staging, MFMA core, pre-packed W) + PAGE
//      PAIRING: the two double-buffer stages are issued back-to-back with
//      consecutive q, so each DRAM page gets one 512B visit instead of two
//      256B visits ~1000cyc apart (halves the activate rate). Pure reorder:
//      LDS layout, occupancy, numerics, epilogue identical to R9 (passed).

#define BB 131072
#define DD 768
#define RPB 128             // rows per block = 4 waves x 32
#define NSUP 12             // K supers (4 x 16-k steps each)
#define SPAN 1040           // 1024B staged + 16B pad (bank-phase shift)
#define BUFO 8320           // 8 spans per buffer
#define WREG 16640          // per-wave LDS: 2 buffers
#define WTU (96 * 32 * 4)   // uints in packed W image (48 KB)

typedef __bf16 bf16x8 __attribute__((ext_vector_type(8)));
typedef float floatx16 __attribute__((ext_vector_type(16)));
typedef unsigned short ushortx8 __attribute__((ext_vector_type(8)));

#define GLOAD_LDS16(gsrc, ldst)                                                \
  __builtin_amdgcn_global_load_lds(                                            \
      (const __attribute__((address_space(1))) void*)(gsrc),                   \
      (__attribute__((address_space(3))) void*)(ldst), 16, 0, 0)

#define WAITV12 asm volatile("s_waitcnt vmcnt(12)" ::: "memory")
#define WAITV0  asm volatile("s_waitcnt vmcnt(0)" ::: "memory")
#define CBAR    asm volatile("" ::: "memory")

__device__ __forceinline__ unsigned bf16_rne(float x) {
  const unsigned u = __builtin_bit_cast(unsigned, x);
  return (u + 0x7fffu + ((u >> 16) & 1u)) >> 16;
}

// x -> hi + mid + lo (bf16-trunc each); gate recovers full f32 product.
__device__ __forceinline__ void cvt3(const float4& a, const float4& b,
                                     bf16x8& H, bf16x8& M, bf16x8& L) {
  const float v[8] = {a.x, a.y, a.z, a.w, b.x, b.y, b.z, b.w};
  ushortx8 h, m, l;
#pragma unroll
  for (int j = 0; j < 8; ++j) {
    const float x = v[j];
    const unsigned ub = __builtin_bit_cast(unsigned, x);
    const float rm = x - __builtin_bit_cast(float, ub & 0xffff0000u);
    const unsigned mb = __builtin_bit_cast(unsigned, rm);
    const float rl = rm - __builtin_bit_cast(float, mb & 0xffff0000u);
    h[j] = (unsigned short)(ub >> 16);
    m[j] = (unsigned short)(mb >> 16);
    l[j] = (unsigned short)(__builtin_bit_cast(unsigned, rl) >> 16);
  }
  H = __builtin_bit_cast(bf16x8, h);
  M = __builtin_bit_cast(bf16x8, m);
  L = __builtin_bit_cast(bf16x8, l);
}

// ---- kernel 1: pack W image into d_ws (R8/R9-verified) ----
// cols 0-5 gate_hi, 6-11 gate_mid, 12-17 gate_lo, 18-29 expert(e*2+l), 30-31 0.
__global__ void pack_w_kernel(const float* __restrict__ gw,
                              const float* __restrict__ ew,
                              unsigned* __restrict__ wt) {
  const int u = blockIdx.x * 256 + threadIdx.x;
  if (u >= WTU) return;
  const int pair = u & 3;
  const int col  = (u >> 2) & 31;
  const int oct  = u >> 7;
  const int k0   = oct * 8 + pair * 2;
  unsigned val = 0;
  if (col < 18) {
    const int part = col / 6, j = col % 6;
    const float w0 = gw[j * DD + k0], w1 = gw[j * DD + k0 + 1];
    const unsigned u0 = __builtin_bit_cast(unsigned, w0);
    const unsigned u1 = __builtin_bit_cast(unsigned, w1);
    const float rm0 = w0 - __builtin_bit_cast(float, u0 & 0xffff0000u);
    const float rm1 = w1 - __builtin_bit_cast(float, u1 & 0xffff0000u);
    const unsigned m0 = __builtin_bit_cast(unsigned, rm0);
    const unsigned m1 = __builtin_bit_cast(unsigned, rm1);
    const float rl0 = rm0 - __builtin_bit_cast(float, m0 & 0xffff0000u);
    const float rl1 = rm1 - __builtin_bit_cast(float, m1 & 0xffff0000u);
    const unsigned l0 = __builtin_bit_cast(unsigned, rl0);
    const unsigned l1 = __builtin_bit_cast(unsigned, rl1);
    if (part == 0)      val = (u0 >> 16) | (u1 & 0xffff0000u);
    else if (part == 1) val = (m0 >> 16) | (m1 & 0xffff0000u);
    else                val = (l0 >> 16) | (l1 & 0xffff0000u);
  } else if (col < 30) {
    const int e = (col - 18) >> 1, l = (col - 18) & 1;
    val = bf16_rne(ew[(e * DD + k0) * 2 + l]) |
          (bf16_rne(ew[(e * DD + k0 + 1) * 2 + l]) << 16);
  }
  wt[u] = val;
}

// ---- kernel 2: main GEMM + argmax-select ----
__global__ __launch_bounds__(256, 2)
void HardMoE_kernel(const float* __restrict__ X,      // [B][768]
                    const unsigned* __restrict__ wtg, // packed W (d_ws)
                    const float* __restrict__ gb,     // [6]
                    const float* __restrict__ eb,     // [6][2]
                    float* __restrict__ out)          // [B][2]
{
  __shared__ char xlds[4 * WREG];   // 66560 B; wave-private regions

  const int tid  = threadIdx.x;
  const int lane = tid & 63;
  const int w    = tid >> 6;
  const int mrow = lane & 31;       // A row in tile; B col
  const int koct = lane >> 5;       // k-octet of the 16-k step

  const int rbase = blockIdx.x * RPB + w * 32;
  char* wb = xlds + w * WREG;
  const float* Xw = X + (size_t)rbase * DD;
  // staging: inst i covers rows 4i..4i+3, 256B contiguous per row
  const int rowoff = (lane >> 4) * DD + (lane & 15) * 4;
  // read: lane's 32B of step t lives at rdoff + t*64
  const int rdoff  = (mrow >> 2) * SPAN + (mrow & 3) * 256 + koct * 32;
  const uint4* wtv = (const uint4*)wtg;
  const int wfo = koct * 32 + mrow; // W frag idx = (q*4+t)*64 + wfo

  auto stage = [&](int bufo, int q) {
#pragma unroll
    for (int i = 0; i < 8; ++i)
      GLOAD_LDS16(Xw + i * 4 * DD + q * 64 + rowoff,
                  wb + bufo + i * SPAN + lane * 16);
  };

  floatx16 acc;
#pragma unroll
  for (int j = 0; j < 16; ++j) acc[j] = 0.f;

  uint4 wvA[4], wvB[4];

  // paired q-walk: pairs (q0+2p, q0+2p+1) mod 12; stagger keeps mod-4 phases
  // {0,3,2,1} across the 4 waves.
  int q0 = 3 * w;
  if (q0 >= NSUP) q0 -= NSUP;
  int qa = q0;
  int qb = (qa + 1 == NSUP) ? 0 : qa + 1;
  // issue order matters for vmcnt counting: [stageA(8), WA(4), stageB(8), WB(4)]
  stage(0, qa); CBAR;
#pragma unroll
  for (int t = 0; t < 4; ++t) wvA[t] = wtv[(qa * 4 + t) * 64 + wfo];
  CBAR;
  stage(BUFO, qb); CBAR;
#pragma unroll
  for (int t = 0; t < 4; ++t) wvB[t] = wtv[(qb * 4 + t) * 64 + wfo];
  CBAR;
  int qn = qb + 1; if (qn >= NSUP) qn -= NSUP;   // next pair start

#define STEP3(bufo, t, WVt)                                                    \
  {                                                                            \
    const char* p = wb + (bufo) + rdoff + (t) * 64;                            \
    const float4 x0 = *(const float4*)p;                                       \
    const float4 x1 = *(const float4*)(p + 16);                                \
    bf16x8 xh, xm, xl;                                                         \
    cvt3(x0, x1, xh, xm, xl);                                                  \
    const bf16x8 bv = __builtin_bit_cast(bf16x8, WVt);                         \
    acc = __builtin_amdgcn_mfma_f32_32x32x16_bf16(xh, bv, acc, 0, 0, 0);       \
    acc = __builtin_amdgcn_mfma_f32_32x32x16_bf16(xm, bv, acc, 0, 0, 0);       \
    acc = __builtin_amdgcn_mfma_f32_32x32x16_bf16(xl, bv, acc, 0, 0, 0);       \
  }

#pragma unroll 1
  for (int p = 0; p < 6; ++p) {
    WAITV12;                              // pair's A (stage+W) landed
    STEP3(0, 0, wvA[0]) STEP3(0, 1, wvA[1])
    STEP3(0, 2, wvA[2]) STEP3(0, 3, wvA[3])
    WAITV0;                               // pair's B landed
    STEP3(BUFO, 0, wvB[0]) STEP3(BUFO, 1, wvB[1])
    STEP3(BUFO, 2, wvB[2]) STEP3(BUFO, 3, wvB[3])
    if (p < 5) {
      // PAGE PAIRING: both stages back-to-back, consecutive q -> each DRAM
      // page visited once with 512B, not twice with 256B.
      const int nqa = qn;
      const int nqb = (nqa + 1 == NSUP) ? 0 : nqa + 1;
      stage(0, nqa); CBAR;
#pragma unroll
      for (int t = 0; t < 4; ++t) wvA[t] = wtv[(nqa * 4 + t) * 64 + wfo];
      CBAR;
      stage(BUFO, nqb); CBAR;
#pragma unroll
      for (int t = 0; t < 4; ++t) wvB[t] = wtv[(nqb * 4 + t) * 64 + wfo];
      CBAR;
      qn = nqb + 1; if (qn >= NSUP) qn -= NSUP;
    }
  }
#undef STEP3

  // ---- epilogue (R7/R8/R9-verified): C col=lane&31, row=(reg&3)+8*(reg>>2)+4*koct
  float* cw = (float*)(xlds + w * WREG);  // reuse wave's own region
#pragma unroll
  for (int reg = 0; reg < 16; ++reg) {
    const int r = (reg & 3) + 8 * (reg >> 2) + 4 * koct;
    const int byteoff = r * 128 + ((mrow * 4) ^ ((r & 7) << 4));
    *(float*)((char*)cw + byteoff) = acc[reg];
  }
  if (lane < 32) {
    const int r = lane;
    float cv[32];
#pragma unroll
    for (int j = 0; j < 8; ++j) {
      const float4 qv = *(const float4*)((const char*)cw + r * 128 +
                                         ((j * 16) ^ ((r & 7) << 4)));
      cv[4 * j] = qv.x; cv[4 * j + 1] = qv.y;
      cv[4 * j + 2] = qv.z; cv[4 * j + 3] = qv.w;
    }
    float g[6];
#pragma unroll
    for (int c = 0; c < 6; ++c) g[c] = cv[c] + cv[6 + c] + cv[12 + c] + gb[c];
    int best = 0; float bv = g[0];
#pragma unroll
    for (int c = 1; c < 6; ++c) { if (g[c] > bv) { bv = g[c]; best = c; } }
    float ebv[12];
#pragma unroll
    for (int i = 0; i < 12; ++i) ebv[i] = eb[i];
    float o0 = cv[18] + ebv[0], o1 = cv[19] + ebv[1];
#pragma unroll
    for (int e = 1; e < 6; ++e) {
      const bool s = (best == e);
      o0 = s ? cv[18 + 2 * e] + ebv[2 * e]     : o0;
      o1 = s ? cv[19 + 2 * e] + ebv[2 * e + 1] : o1;
    }
    ((float2*)out)[rbase + r] = make_float2(o0, o1);
  }
}

extern "C" void kernel_launch(void* const* d_in, const int* in_sizes, int n_in,
                              void* d_out, int out_size, void* d_ws, size_t ws_size,
                              hipStream_t stream) {
  (void)in_sizes; (void)n_in; (void)ws_size; (void)out_size;
  const float* X  = (const float*)d_in[0];
  const float* gw = (const float*)d_in[1];
  const float* gb = (const float*)d_in[2];
  const float* ew = (const float*)d_in[3];
  const float* eb = (const float*)d_in[4];
  float* out = (float*)d_out;
  unsigned* wt = (unsigned*)d_ws;   // 48 KB

  pack_w_kernel<<<WTU / 256, 256, 0, stream>>>(gw, ew, wt);
  HardMoE_kernel<<<BB / RPB, 256, 0, stream>>>(X, wt, gb, eb, out);
}